// Round 3
// baseline (346.621 us; speedup 1.0000x reference)
//
#include <hip/hip_runtime.h>

typedef unsigned short u16;
typedef __attribute__((ext_vector_type(8))) short bf16x8;
typedef __attribute__((ext_vector_type(8))) unsigned short u16x8;
typedef __attribute__((ext_vector_type(4))) float f32x4;

static __device__ __forceinline__ u16 f2bf(float f) {
  unsigned u = __float_as_uint(f);
  u += 0x7FFFu + ((u >> 16) & 1u);   // RNE
  return (u16)(u >> 16);
}
static __device__ __forceinline__ float bf2f(u16 h) {
  return __uint_as_float(((unsigned)h) << 16);
}

// ---------------- fp32 -> bf16 convert, 8 elems/thread ----------------
__global__ __launch_bounds__(256) void f2bf_vec(const float* __restrict__ in,
                                                u16* __restrict__ out, int n8) {
  int i = blockIdx.x * 256 + threadIdx.x;
  if (i >= n8) return;
  const float4* p = (const float4*)in + (size_t)i * 2;
  float4 a = p[0], b = p[1];
  u16x8 r;
  r[0] = f2bf(a.x); r[1] = f2bf(a.y); r[2] = f2bf(a.z); r[3] = f2bf(a.w);
  r[4] = f2bf(b.x); r[5] = f2bf(b.y); r[6] = f2bf(b.z); r[7] = f2bf(b.w);
  ((u16x8*)out)[i] = r;
}

// ---------------- row-sum of K (bf16, 1024 cols) -> fp32 ----------------
__global__ __launch_bounds__(256) void ksum_kernel(const u16* __restrict__ K,
                                                   float* __restrict__ out) {
  int row = blockIdx.x * 4 + (threadIdx.x >> 6);
  int lane = threadIdx.x & 63;
  const u16x8* p = (const u16x8*)(K + (size_t)row * 1024);
  float s = 0.f;
#pragma unroll
  for (int it = 0; it < 2; ++it) {
    u16x8 v = p[lane + it * 64];
#pragma unroll
    for (int j = 0; j < 8; ++j) s += bf2f(v[j]);
  }
#pragma unroll
  for (int off = 32; off >= 1; off >>= 1) s += __shfl_down(s, off);
  if (lane == 0) out[row] = s;
}

// =============== 256x256 bf16 GEMM engine, C = A(MxK) * B(NxK)^T ===============
// m201-style 8-phase schedule: per K-tile, 4 phases of
//   {ds_read subtile | prefetch global_load_lds | barrier | lgkmcnt(0) |
//    setprio(1) 16xMFMA setprio(0) | barrier}
// double-buffered 128KB LDS, T2 XOR swizzle (inverse-swizzled global source,
// swizzled ds_read), counted boundary drain, T5 setprio, T1 XCD swizzle.
enum { M_BIASN = 0, M_BIASM = 1, M_SCORES = 2, M_OUT = 3 };

#define SBAR __builtin_amdgcn_sched_barrier(0)
#define WGB  __builtin_amdgcn_s_barrier()
#define LG0  asm volatile("s_waitcnt lgkmcnt(0)" ::: "memory")
#define VM0  asm volatile("s_waitcnt vmcnt(0)" ::: "memory")

template <int MODE>
__global__ __launch_bounds__(512, 2) void gemm_bt(
    const u16* __restrict__ A, int lda, long long sA,
    const u16* __restrict__ B, int ldb, long long sB,
    void* __restrict__ Cv, int ldc, long long sC,
    int k_len, const float* __restrict__ bias,
    const float* __restrict__ ksum, const float* __restrict__ vtab, int Tdim) {
  // ---- bijective XCD swizzle (nl % 8 == 0 for all our grids) ----
  const int nl = gridDim.x * gridDim.y;
  const int l = blockIdx.x + gridDim.x * blockIdx.y;
  const int q8 = nl >> 3;
  const int logical = (l & 7) * q8 + (l >> 3);
  const int gx = logical % gridDim.x;
  const int gy = logical / gridDim.x;
  const int z = blockIdx.z;

  if (MODE == M_SCORES && gx > gy) return;  // upper-triangle tiles never read

  const u16* Ab = A + (size_t)z * sA;
  const u16* Bb = B + (size_t)z * sB;
  const int n0 = gx * 256;

  __shared__ char smem[131072];  // 2 x (A 32KB + B 32KB)

  const int tid = threadIdx.x;
  const int lane = tid & 63;
  const int wid = tid >> 6;
  const int wm = wid >> 2, wn = wid & 3;  // 2 x 4 wave grid, wave owns 128x64

  // staging geometry: issue i moves rows [64i, 64i+64) of one matrix (8KB).
  // LDS dest linear; global source column carries the inverse XOR swizzle.
  int srow[4], scol[4];
#pragma unroll
  for (int i = 0; i < 4; ++i) {
    int f = tid * 16 + i * 8192;
    int row = f >> 7;  // 128B per 64-col bf16 row
    int cb = f & 127;
    srow[i] = row;
    scol[i] = cb ^ ((row & 7) << 4);
  }

  // per-thread LDS read constants (fragment rows have r&7 == lane&7)
  const int aoff = wm * 16384 + (lane & 15) * 128;
  const int boff = wn * 8192 + (lane & 15) * 128;
  const int c0 = (((0 * 4 + (lane >> 4)) ^ (lane & 7)) << 4);  // ks=0 swizzled col
  const int c1 = (((1 * 4 + (lane >> 4)) ^ (lane & 7)) << 4);  // ks=1 swizzled col

  const float* ksb = (MODE == M_SCORES) ? (ksum + (size_t)z * Tdim) : nullptr;
  u16* Cb16 = (u16*)Cv + (size_t)z * sC;
  float* Cf = (float*)Cv + (size_t)z * sC;

#define STAGE2(kt_, buf_, i_)                                                   \
  {                                                                             \
    const int k0_ = (kt_) * 64;                                                 \
    char* As_ = smem + (buf_) * 65536;                                          \
    char* Bs_ = As_ + 32768;                                                    \
    const char* ga = (const char*)(Ab + (size_t)(m0 + srow[i_]) * lda + k0_) + scol[i_]; \
    const char* gb = (const char*)(Bb + (size_t)(n0 + srow[i_]) * ldb + k0_) + scol[i_]; \
    __builtin_amdgcn_global_load_lds(                                           \
        (const __attribute__((address_space(1))) void*)ga,                      \
        (__attribute__((address_space(3))) void*)(As_ + (i_) * 8192 + wid * 1024), 16, 0, 0); \
    __builtin_amdgcn_global_load_lds(                                           \
        (const __attribute__((address_space(1))) void*)gb,                      \
        (__attribute__((address_space(3))) void*)(Bs_ + (i_) * 8192 + wid * 1024), 16, 0, 0); \
  }

#define LDA4(dst, mh, cks)                                                      \
  { _Pragma("unroll") for (int i_ = 0; i_ < 4; ++i_)                            \
      dst[i_] = *(const bf16x8*)(As + aoff + ((mh) * 4 + i_) * 2048 + (cks)); }
#define LDB4(dst, cks)                                                          \
  { _Pragma("unroll") for (int i_ = 0; i_ < 4; ++i_)                            \
      dst[i_] = *(const bf16x8*)(Bs + boff + i_ * 2048 + (cks)); }
#define MM16(mb, af_, bf_)                                                      \
  { _Pragma("unroll") for (int m_ = 0; m_ < 4; ++m_)                            \
      _Pragma("unroll") for (int n_ = 0; n_ < 4; ++n_)                          \
        acc[(mb) + m_][n_] = __builtin_amdgcn_mfma_f32_16x16x32_bf16(           \
            af_[m_], bf_[n_], acc[(mb) + m_][n_], 0, 0, 0); }

  const int nsub = (MODE == M_OUT) ? 2 : 1;
  for (int sub = 0; sub < nsub; ++sub) {
    const int gye = (MODE == M_OUT) ? (sub ? 7 - gy : gy) : gy;
    const int m0 = gye * 256;
    const int kl = (MODE == M_OUT) ? (gye + 1) * 256 : k_len;  // causal K-extent
    const int nk = kl >> 6;

    f32x4 acc[8][4];
#pragma unroll
    for (int m = 0; m < 8; ++m)
#pragma unroll
      for (int n = 0; n < 4; ++n) acc[m][n] = (f32x4){0.f, 0.f, 0.f, 0.f};

    // prologue: stage tile 0 fully into buf0
#pragma unroll
    for (int i = 0; i < 4; ++i) STAGE2(0, 0, i);
    VM0;
    SBAR;
    WGB;

    for (int kt = 0; kt < nk; ++kt) {
      const int cur = kt & 1;
      const char* As = smem + cur * 65536;
      const char* Bs = As + 32768;
      const bool pf = (kt + 1 < nk);
      bf16x8 afa[4], afb[4], bfa[4], bfb[4];

      // ---- phase 0: (mh0, ks0) ----
      LDA4(afa, 0, c0);
      LDB4(bfa, c0);
      if (pf) { STAGE2(kt + 1, cur ^ 1, 0); STAGE2(kt + 1, cur ^ 1, 1); }
      SBAR; WGB; LG0; SBAR;
      __builtin_amdgcn_s_setprio(1);
      MM16(0, afa, bfa);
      __builtin_amdgcn_s_setprio(0);
      SBAR; WGB;

      // ---- phase 1: (mh1, ks0), reuse bfa ----
      LDA4(afb, 1, c0);
      if (pf) { STAGE2(kt + 1, cur ^ 1, 2); STAGE2(kt + 1, cur ^ 1, 3); }
      SBAR; WGB; LG0; SBAR;
      __builtin_amdgcn_s_setprio(1);
      MM16(4, afb, bfa);
      __builtin_amdgcn_s_setprio(0);
      SBAR; WGB;

      // ---- phase 2: (mh0, ks1) ----
      LDA4(afa, 0, c1);
      LDB4(bfb, c1);
      SBAR; WGB; LG0; SBAR;
      __builtin_amdgcn_s_setprio(1);
      MM16(0, afa, bfb);
      __builtin_amdgcn_s_setprio(0);
      SBAR; WGB;

      // ---- phase 3: (mh1, ks1), reuse bfb; boundary drain ----
      LDA4(afb, 1, c1);
      SBAR; WGB; LG0; SBAR;
      __builtin_amdgcn_s_setprio(1);
      MM16(4, afb, bfb);
      __builtin_amdgcn_s_setprio(0);
      SBAR;
      if (pf) VM0;  // tile kt+1 fully resident before next iter's reads
      SBAR;
      WGB;
    }

    // epilogue — C/D layout: col = lane&15, row = (lane>>4)*4 + reg  [m89]
#pragma unroll
    for (int m = 0; m < 8; ++m) {
#pragma unroll
      for (int n = 0; n < 4; ++n) {
        const int rbase = m0 + wm * 128 + m * 16 + ((lane >> 4) << 2);
        const int c = n0 + wn * 64 + n * 16 + (lane & 15);
#pragma unroll
        for (int j = 0; j < 4; ++j) {
          const int r = rbase + j;
          float v = acc[m][n][j];
          if (MODE == M_BIASN) {
            v += bias[c];
            Cb16[(size_t)r * ldc + c] = f2bf(v);
          } else if (MODE == M_BIASM) {
            v += bias[r];
            Cb16[(size_t)r * ldc + c] = f2bf(v);
          } else if (MODE == M_SCORES) {
            if (c <= r) v += ksb[r] * vtab[r - c];  // rel = t-s >= 0
            else v = 0.f;                           // causal mask
            Cb16[(size_t)r * ldc + c] = f2bf(v);
          } else {  // M_OUT
            Cf[(size_t)r * ldc + c] = v;
          }
        }
      }
    }
  }
#undef STAGE2
#undef LDA4
#undef LDB4
#undef MM16
}

extern "C" void kernel_launch(void* const* d_in, const int* in_sizes, int n_in,
                              void* d_out, int out_size, void* d_ws, size_t ws_size,
                              hipStream_t stream) {
  (void)in_sizes; (void)n_in; (void)out_size; (void)ws_size;
  const float* e    = (const float*)d_in[0];
  const float* res  = (const float*)d_in[1];
  const float* Wq_w = (const float*)d_in[2];
  const float* Wq_b = (const float*)d_in[3];
  const float* Wk_w = (const float*)d_in[4];
  const float* Wk_b = (const float*)d_in[5];
  const float* Wv_w = (const float*)d_in[6];
  const float* Wv_b = (const float*)d_in[7];
  const float* vtab = (const float*)d_in[8];

  const int T = 2048, D = 1024, Bn = 8;
  const size_t BT = (size_t)Bn * T;     // 16384
  const size_t ND = BT * (size_t)D;     // 16,777,216 elements

  char* ws = (char*)d_ws;
  const size_t SZ = 33554432;  // 32 MiB = one bf16 (16384x1024) buffer
  u16* ebf = (u16*)(ws);
  u16* rbf = (u16*)(ws + SZ);
  u16* Qb  = (u16*)(ws + 2 * SZ);
  u16* Kb  = (u16*)(ws + 3 * SZ);
  u16* VT  = (u16*)(ws + 4 * SZ);
  u16* Wqb = (u16*)(ws + 5 * SZ);
  u16* Wkb = (u16*)(ws + 5 * SZ + 2097152);
  u16* Wvb = (u16*)(ws + 5 * SZ + 2 * 2097152);
  float* ksum = (float*)(ws + 5 * SZ + 3 * 2097152);
  u16* scores = (u16*)(ws);  // reuse ebf+rbf (67 MB), safe: last read is VT gemm

  // fp32 -> bf16
  f2bf_vec<<<(int)(ND / 8 / 256), 256, 0, stream>>>(e, ebf, (int)(ND / 8));
  f2bf_vec<<<(int)(ND / 8 / 256), 256, 0, stream>>>(res, rbf, (int)(ND / 8));
  f2bf_vec<<<512, 256, 0, stream>>>(Wq_w, Wqb, 131072);
  f2bf_vec<<<512, 256, 0, stream>>>(Wk_w, Wkb, 131072);
  f2bf_vec<<<512, 256, 0, stream>>>(Wv_w, Wvb, 131072);

  // Q = e @ Wq^T + bq   (16384x1024), 256^2 tiles -> grid (4, 64)
  gemm_bt<M_BIASN><<<dim3(4, 64, 1), 512, 0, stream>>>(
      ebf, D, 0, Wqb, D, 0, (void*)Qb, D, 0, D, Wq_b, nullptr, nullptr, T);
  // K = res @ Wk^T + bk
  gemm_bt<M_BIASN><<<dim3(4, 64, 1), 512, 0, stream>>>(
      rbf, D, 0, Wkb, D, 0, (void*)Kb, D, 0, D, Wk_b, nullptr, nullptr, T);
  // V^T[d, b*T+t] = Wv @ e^T + bv (bias per row d) -> coalesced stores; gives
  // the out-pass its (N x K) K-contiguous B operand.
  gemm_bt<M_BIASM><<<dim3(64, 4, 1), 512, 0, stream>>>(
      Wvb, D, 0, ebf, D, 0, (void*)VT, (int)BT, 0, D, Wv_b, nullptr, nullptr, T);

  // Ksum[b,t]
  ksum_kernel<<<4096, 256, 0, stream>>>(Kb, ksum);

  // scores[b,t,s] = Q.K^T + Ksum[t]*v[t-s], causal, bf16 (lower-tri tiles only)
  gemm_bt<M_SCORES><<<dim3(8, 8, 8), 512, 0, stream>>>(
      Qb, D, (long long)T * D, Kb, D, (long long)T * D, (void*)scores, T,
      (long long)T * T, D, nullptr, ksum, vtab, T);

  // out[b,t,d] = scores @ V, K truncated at causal boundary; blocks pair
  // gy with 7-gy so every block does exactly 36 K-tiles (load balance).
  gemm_bt<M_OUT><<<dim3(4, 4, 8), 512, 0, stream>>>(
      scores, T, (long long)T * T, VT, (int)BT, T, d_out, D, (long long)T * D,
      0, nullptr, nullptr, nullptr, T);
}

// Round 4
// 336.332 us; speedup vs baseline: 1.0306x; 1.0306x over previous
//
#include <hip/hip_runtime.h>

typedef unsigned short u16;
typedef __attribute__((ext_vector_type(8))) short bf16x8;
typedef __attribute__((ext_vector_type(8))) unsigned short u16x8;
typedef __attribute__((ext_vector_type(4))) float f32x4;

static __device__ __forceinline__ u16 f2bf(float f) {
  unsigned u = __float_as_uint(f);
  u += 0x7FFFu + ((u >> 16) & 1u);   // RNE
  return (u16)(u >> 16);
}
static __device__ __forceinline__ float bf2f(u16 h) {
  return __uint_as_float(((unsigned)h) << 16);
}

// ---------------- fp32 -> bf16 convert, 8 elems/thread ----------------
__global__ __launch_bounds__(256) void f2bf_vec(const float* __restrict__ in,
                                                u16* __restrict__ out, int n8) {
  int i = blockIdx.x * 256 + threadIdx.x;
  if (i >= n8) return;
  const float4* p = (const float4*)in + (size_t)i * 2;
  float4 a = p[0], b = p[1];
  u16x8 r;
  r[0] = f2bf(a.x); r[1] = f2bf(a.y); r[2] = f2bf(a.z); r[3] = f2bf(a.w);
  r[4] = f2bf(b.x); r[5] = f2bf(b.y); r[6] = f2bf(b.z); r[7] = f2bf(b.w);
  ((u16x8*)out)[i] = r;
}

// ---------------- row-sum of K (bf16, 1024 cols) -> fp32 ----------------
__global__ __launch_bounds__(256) void ksum_kernel(const u16* __restrict__ K,
                                                   float* __restrict__ out) {
  int row = blockIdx.x * 4 + (threadIdx.x >> 6);
  int lane = threadIdx.x & 63;
  const u16x8* p = (const u16x8*)(K + (size_t)row * 1024);
  float s = 0.f;
#pragma unroll
  for (int it = 0; it < 2; ++it) {
    u16x8 v = p[lane + it * 64];
#pragma unroll
    for (int j = 0; j < 8; ++j) s += bf2f(v[j]);
  }
#pragma unroll
  for (int off = 32; off >= 1; off >>= 1) s += __shfl_down(s, off);
  if (lane == 0) out[row] = s;
}

// =============== 256x256 bf16 GEMM engine, C = A(MxK) * B(NxK)^T ===============
// T3+T4: 4 phases/K-tile, next tile staged in phases 0-1, ONE counted
// s_waitcnt vmcnt(4) per K-tile at phase-0 top (loads stay in flight across
// barriers, never drain to 0 mid-loop — m218's isolated +38-73% lever).
// T2 XOR swizzle (inverse-swizzled global source + swizzled ds_read),
// T5 setprio around MFMA clusters, T1 bijective XCD swizzle.
enum { M_BIASN = 0, M_BIASM = 1, M_SCORES = 2, M_OUT = 3 };

#define SBAR __builtin_amdgcn_sched_barrier(0)
#define WGB  __builtin_amdgcn_s_barrier()
#define LG0  asm volatile("s_waitcnt lgkmcnt(0)" ::: "memory")

template <int MODE>
static __device__ __forceinline__ void gemm_engine(
    const u16* __restrict__ A, int lda, long long sA,
    const u16* __restrict__ B, int ldb, long long sB,
    void* __restrict__ Cv, int ldc, long long sC,
    int k_len, const float* __restrict__ bias,
    const float* __restrict__ ksum, const float* __restrict__ vtab, int Tdim) {
  // ---- bijective XCD swizzle (nl % 8 == 0 for all our grids) ----
  const int nl = gridDim.x * gridDim.y;
  const int l = blockIdx.x + gridDim.x * blockIdx.y;
  const int q8 = nl >> 3;
  const int logical = (l & 7) * q8 + (l >> 3);
  const int gx = logical % gridDim.x;
  const int gy = logical / gridDim.x;
  const int z = blockIdx.z;

  if (MODE == M_SCORES && gx > gy) return;  // upper-triangle tiles never read
  const int kl = (MODE == M_OUT) ? (gy + 1) * 256 : k_len;  // causal K-extent
  const int nk = kl >> 6;

  const u16* Ab = A + (size_t)z * sA;
  const u16* Bb = B + (size_t)z * sB;
  const int m0 = gy * 256, n0 = gx * 256;

  __shared__ char smem[131072];  // 2 x (A 32KB + B 32KB)

  const int tid = threadIdx.x;
  const int lane = tid & 63;
  const int wid = tid >> 6;
  const int wm = wid >> 2, wn = wid & 3;  // 2 x 4 wave grid, wave owns 128x64

  // staging geometry: unit i = rows [64i,64i+64) of A and of B (2 loads/thr).
  // LDS dest linear; global source column carries the inverse XOR swizzle.
  int srow[4], scol[4];
#pragma unroll
  for (int i = 0; i < 4; ++i) {
    int f = tid * 16 + i * 8192;
    int row = f >> 7;  // 128B per 64-col bf16 row
    int cb = f & 127;
    srow[i] = row;
    scol[i] = cb ^ ((row & 7) << 4);
  }

  // per-thread LDS read constants (fragment rows have r&7 == lane&7)
  const int aoff = wm * 16384 + (lane & 15) * 128;
  const int boff = wn * 8192 + (lane & 15) * 128;
  const int c0 = (((0 * 4 + (lane >> 4)) ^ (lane & 7)) << 4);  // ks=0 swizzled col
  const int c1 = (((1 * 4 + (lane >> 4)) ^ (lane & 7)) << 4);  // ks=1 swizzled col

  f32x4 acc[8][4];
#pragma unroll
  for (int m = 0; m < 8; ++m)
#pragma unroll
    for (int n = 0; n < 4; ++n) acc[m][n] = (f32x4){0.f, 0.f, 0.f, 0.f};

#define STAGE2(kt_, buf_, i_)                                                   \
  {                                                                             \
    const int k0_ = (kt_) * 64;                                                 \
    char* As_ = smem + (buf_) * 65536;                                          \
    char* Bs_ = As_ + 32768;                                                    \
    const char* ga = (const char*)(Ab + (size_t)(m0 + srow[i_]) * lda + k0_) + scol[i_]; \
    const char* gb = (const char*)(Bb + (size_t)(n0 + srow[i_]) * ldb + k0_) + scol[i_]; \
    __builtin_amdgcn_global_load_lds(                                           \
        (const __attribute__((address_space(1))) void*)ga,                      \
        (__attribute__((address_space(3))) void*)(As_ + (i_) * 8192 + wid * 1024), 16, 0, 0); \
    __builtin_amdgcn_global_load_lds(                                           \
        (const __attribute__((address_space(1))) void*)gb,                      \
        (__attribute__((address_space(3))) void*)(Bs_ + (i_) * 8192 + wid * 1024), 16, 0, 0); \
  }

#define LDA4(dst, mh, cks)                                                      \
  { _Pragma("unroll") for (int i_ = 0; i_ < 4; ++i_)                            \
      dst[i_] = *(const bf16x8*)(As + aoff + ((mh) * 4 + i_) * 2048 + (cks)); }
#define LDB4(dst, cks)                                                          \
  { _Pragma("unroll") for (int i_ = 0; i_ < 4; ++i_)                            \
      dst[i_] = *(const bf16x8*)(Bs + boff + i_ * 2048 + (cks)); }
#define MM16(mb, af_, bf_)                                                      \
  { _Pragma("unroll") for (int m_ = 0; m_ < 4; ++m_)                            \
      _Pragma("unroll") for (int n_ = 0; n_ < 4; ++n_)                          \
        acc[(mb) + m_][n_] = __builtin_amdgcn_mfma_f32_16x16x32_bf16(           \
            af_[m_], bf_[n_], acc[(mb) + m_][n_], 0, 0, 0); }

  // prologue: stage all 4 units of tile 0 into buf0 (8 loads in flight)
#pragma unroll
  for (int i = 0; i < 4; ++i) STAGE2(0, 0, i);

  for (int kt = 0; kt < nk; ++kt) {
    const int cur = kt & 1;
    const char* As = smem + cur * 65536;
    const char* Bs = As + 32768;
    const bool pf = (kt + 1 < nk);
    bf16x8 afa[4], afb[4], bfa[4], bfb[4];

    // ---- phase 0: (mh0, ks0); counted wait for tile kt, kt+1 units 0-1 fly ----
    if (pf) { STAGE2(kt + 1, cur ^ 1, 0); STAGE2(kt + 1, cur ^ 1, 1); }
    if (pf) asm volatile("s_waitcnt vmcnt(4)" ::: "memory");  // tile kt landed
    else    asm volatile("s_waitcnt vmcnt(0)" ::: "memory");
    WGB;   // all waves' tile-kt LDS stores now visible
    SBAR;  // pin: no buf-cur reads hoisted above this point
    LDA4(afa, 0, c0);
    LDB4(bfa, c0);
    LG0; SBAR;
    __builtin_amdgcn_s_setprio(1);
    MM16(0, afa, bfa);
    __builtin_amdgcn_s_setprio(0);
    WGB;

    // ---- phase 1: (mh1, ks0), reuse bfa; stage kt+1 units 2-3 ----
    LDA4(afb, 1, c0);
    if (pf) { STAGE2(kt + 1, cur ^ 1, 2); STAGE2(kt + 1, cur ^ 1, 3); }
    WGB; LG0; SBAR;
    __builtin_amdgcn_s_setprio(1);
    MM16(4, afb, bfa);
    __builtin_amdgcn_s_setprio(0);
    WGB;

    // ---- phase 2: (mh0, ks1) ----
    LDA4(afa, 0, c1);
    LDB4(bfb, c1);
    WGB; LG0; SBAR;
    __builtin_amdgcn_s_setprio(1);
    MM16(0, afa, bfb);
    __builtin_amdgcn_s_setprio(0);
    WGB;

    // ---- phase 3: (mh1, ks1), reuse bfb; NO vmem drain here ----
    LDA4(afb, 1, c1);
    WGB; LG0; SBAR;
    __builtin_amdgcn_s_setprio(1);
    MM16(4, afb, bfb);
    __builtin_amdgcn_s_setprio(0);
    WGB;
  }

  // epilogue — C/D layout: col = lane&15, row = (lane>>4)*4 + reg  [m89]
  const float* ksb = (MODE == M_SCORES) ? (ksum + (size_t)z * Tdim) : nullptr;
  u16* Cb16 = (u16*)Cv + (size_t)z * sC;
  float* Cf = (float*)Cv + (size_t)z * sC;

#pragma unroll
  for (int m = 0; m < 8; ++m) {
#pragma unroll
    for (int n = 0; n < 4; ++n) {
      const int rbase = m0 + wm * 128 + m * 16 + ((lane >> 4) << 2);
      const int c = n0 + wn * 64 + n * 16 + (lane & 15);
#pragma unroll
      for (int j = 0; j < 4; ++j) {
        const int r = rbase + j;
        float v = acc[m][n][j];
        if (MODE == M_BIASN) {
          v += bias[c];
          Cb16[(size_t)r * ldc + c] = f2bf(v);
        } else if (MODE == M_BIASM) {
          v += bias[r];
          Cb16[(size_t)r * ldc + c] = f2bf(v);
        } else if (MODE == M_SCORES) {
          if (c <= r) v += ksb[r] * vtab[r - c];  // rel = t-s >= 0
          else v = 0.f;                           // causal mask
          Cb16[(size_t)r * ldc + c] = f2bf(v);
        } else {  // M_OUT
          Cf[(size_t)r * ldc + c] = v;
        }
      }
    }
  }
#undef STAGE2
#undef LDA4
#undef LDB4
#undef MM16
}

// Distinct kernel names per pass for unambiguous rocprof attribution.
#define ENG_PARAMS                                                              \
  const u16* A, int lda, long long sA, const u16* B, int ldb, long long sB,     \
  void* Cv, int ldc, long long sC, int k_len, const float* bias,                \
  const float* ksum, const float* vtab, int Tdim
#define ENG_ARGS A, lda, sA, B, ldb, sB, Cv, ldc, sC, k_len, bias, ksum, vtab, Tdim

__global__ __launch_bounds__(512, 2) void k_q_proj(ENG_PARAMS)  { gemm_engine<M_BIASN >(ENG_ARGS); }
__global__ __launch_bounds__(512, 2) void k_k_proj(ENG_PARAMS)  { gemm_engine<M_BIASN >(ENG_ARGS); }
__global__ __launch_bounds__(512, 2) void k_v_proj(ENG_PARAMS)  { gemm_engine<M_BIASM >(ENG_ARGS); }
__global__ __launch_bounds__(512, 2) void k_scores(ENG_PARAMS)  { gemm_engine<M_SCORES>(ENG_ARGS); }
__global__ __launch_bounds__(512, 2) void k_out(ENG_PARAMS)     { gemm_engine<M_OUT   >(ENG_ARGS); }

extern "C" void kernel_launch(void* const* d_in, const int* in_sizes, int n_in,
                              void* d_out, int out_size, void* d_ws, size_t ws_size,
                              hipStream_t stream) {
  (void)in_sizes; (void)n_in; (void)out_size; (void)ws_size;
  const float* e    = (const float*)d_in[0];
  const float* res  = (const float*)d_in[1];
  const float* Wq_w = (const float*)d_in[2];
  const float* Wq_b = (const float*)d_in[3];
  const float* Wk_w = (const float*)d_in[4];
  const float* Wk_b = (const float*)d_in[5];
  const float* Wv_w = (const float*)d_in[6];
  const float* Wv_b = (const float*)d_in[7];
  const float* vtab = (const float*)d_in[8];

  const int T = 2048, D = 1024, Bn = 8;
  const size_t BT = (size_t)Bn * T;     // 16384
  const size_t ND = BT * (size_t)D;     // 16,777,216 elements

  char* ws = (char*)d_ws;
  const size_t SZ = 33554432;  // 32 MiB = one bf16 (16384x1024) buffer
  u16* ebf = (u16*)(ws);
  u16* rbf = (u16*)(ws + SZ);
  u16* Qb  = (u16*)(ws + 2 * SZ);
  u16* Kb  = (u16*)(ws + 3 * SZ);
  u16* VT  = (u16*)(ws + 4 * SZ);
  u16* Wqb = (u16*)(ws + 5 * SZ);
  u16* Wkb = (u16*)(ws + 5 * SZ + 2097152);
  u16* Wvb = (u16*)(ws + 5 * SZ + 2 * 2097152);
  float* ksum = (float*)(ws + 5 * SZ + 3 * 2097152);
  u16* scores = (u16*)(ws);  // reuse ebf+rbf (67 MB), safe: last read is VT gemm

  // fp32 -> bf16
  f2bf_vec<<<(int)(ND / 8 / 256), 256, 0, stream>>>(e, ebf, (int)(ND / 8));
  f2bf_vec<<<(int)(ND / 8 / 256), 256, 0, stream>>>(res, rbf, (int)(ND / 8));
  f2bf_vec<<<512, 256, 0, stream>>>(Wq_w, Wqb, 131072);
  f2bf_vec<<<512, 256, 0, stream>>>(Wk_w, Wkb, 131072);
  f2bf_vec<<<512, 256, 0, stream>>>(Wv_w, Wvb, 131072);

  // Q = e @ Wq^T + bq   (16384x1024), 256^2 tiles -> grid (4, 64)
  k_q_proj<<<dim3(4, 64, 1), 512, 0, stream>>>(
      ebf, D, 0, Wqb, D, 0, (void*)Qb, D, 0, D, Wq_b, nullptr, nullptr, T);
  // K = res @ Wk^T + bk
  k_k_proj<<<dim3(4, 64, 1), 512, 0, stream>>>(
      rbf, D, 0, Wkb, D, 0, (void*)Kb, D, 0, D, Wk_b, nullptr, nullptr, T);
  // V^T[d, b*T+t] = Wv @ e^T + bv (bias per row d) -> coalesced stores; gives
  // the out-pass its (N x K) K-contiguous B operand.
  k_v_proj<<<dim3(64, 4, 1), 512, 0, stream>>>(
      Wvb, D, 0, ebf, D, 0, (void*)VT, (int)BT, 0, D, Wv_b, nullptr, nullptr, T);

  // Ksum[b,t]
  ksum_kernel<<<4096, 256, 0, stream>>>(Kb, ksum);

  // scores[b,t,s] = Q.K^T + Ksum[t]*v[t-s], causal, bf16 (lower-tri tiles only)
  k_scores<<<dim3(8, 8, 8), 512, 0, stream>>>(
      Qb, D, (long long)T * D, Kb, D, (long long)T * D, (void*)scores, T,
      (long long)T * T, D, nullptr, ksum, vtab, T);

  // out[b,t,d] = scores @ V, K truncated at causal boundary (256 blocks)
  k_out<<<dim3(4, 8, 8), 512, 0, stream>>>(
      scores, T, (long long)T * T, VT, (int)BT, T, d_out, D, (long long)T * D,
      0, nullptr, nullptr, nullptr, T);
}

// Round 5
// 304.428 us; speedup vs baseline: 1.1386x; 1.1048x over previous
//
#include <hip/hip_runtime.h>

typedef unsigned short u16;
typedef __attribute__((ext_vector_type(8))) short bf16x8;
typedef __attribute__((ext_vector_type(8))) unsigned short u16x8;
typedef __attribute__((ext_vector_type(4))) float f32x4;

static __device__ __forceinline__ u16 f2bf(float f) {
  unsigned u = __float_as_uint(f);
  u += 0x7FFFu + ((u >> 16) & 1u);   // RNE
  return (u16)(u >> 16);
}
static __device__ __forceinline__ float bf2f(u16 h) {
  return __uint_as_float(((unsigned)h) << 16);
}

// ---------- fp32 -> bf16 converts (fused via grid.z) ----------
__global__ __launch_bounds__(256) void conv_big(const float* __restrict__ e,
                                                const float* __restrict__ res,
                                                u16* __restrict__ eb, u16* __restrict__ rb) {
  int i = blockIdx.x * 256 + threadIdx.x;  // 8192 blocks -> i < 2097152 (x8 elems)
  const float* in = blockIdx.z ? res : e;
  u16* out = blockIdx.z ? rb : eb;
  const float4* p = (const float4*)in + (size_t)i * 2;
  float4 a = p[0], b = p[1];
  u16x8 r;
  r[0] = f2bf(a.x); r[1] = f2bf(a.y); r[2] = f2bf(a.z); r[3] = f2bf(a.w);
  r[4] = f2bf(b.x); r[5] = f2bf(b.y); r[6] = f2bf(b.z); r[7] = f2bf(b.w);
  ((u16x8*)out)[i] = r;
}
__global__ __launch_bounds__(256) void conv_w(const float* __restrict__ w0,
                                              const float* __restrict__ w1,
                                              const float* __restrict__ w2,
                                              u16* __restrict__ o0, u16* __restrict__ o1,
                                              u16* __restrict__ o2) {
  int i = blockIdx.x * 256 + threadIdx.x;  // 512 blocks -> i < 131072
  const float* in = blockIdx.z == 0 ? w0 : (blockIdx.z == 1 ? w1 : w2);
  u16* out = blockIdx.z == 0 ? o0 : (blockIdx.z == 1 ? o1 : o2);
  const float4* p = (const float4*)in + (size_t)i * 2;
  float4 a = p[0], b = p[1];
  u16x8 r;
  r[0] = f2bf(a.x); r[1] = f2bf(a.y); r[2] = f2bf(a.z); r[3] = f2bf(a.w);
  r[4] = f2bf(b.x); r[5] = f2bf(b.y); r[6] = f2bf(b.z); r[7] = f2bf(b.w);
  ((u16x8*)out)[i] = r;
}

// ---------- row-sum of K (bf16, 1024 cols) -> fp32 ----------
__global__ __launch_bounds__(256) void ksum_kernel(const u16* __restrict__ K,
                                                   float* __restrict__ out) {
  int row = blockIdx.x * 4 + (threadIdx.x >> 6);
  int lane = threadIdx.x & 63;
  const u16x8* p = (const u16x8*)(K + (size_t)row * 1024);
  float s = 0.f;
#pragma unroll
  for (int it = 0; it < 2; ++it) {
    u16x8 v = p[lane + it * 64];
#pragma unroll
    for (int j = 0; j < 8; ++j) s += bf2f(v[j]);
  }
#pragma unroll
  for (int off = 32; off >= 1; off >>= 1) s += __shfl_down(s, off);
  if (lane == 0) out[row] = s;
}

// =============== 256x128 bf16 GEMM core, C = A(MxK) * B(NxK)^T ===============
// m97 structure: single 48KB LDS buffer, 2 __syncthreads per K-step, 8 waves
// (4M x 2N, wave tile 64x64, acc 4x4), global_load_lds width 16. SWZ selects
// XOR-swizzled (T2) vs linear (m97-exact) LDS layout — A/B'd via k_q vs k_k.
enum { M_BIASN = 0, M_BIASM = 1, M_SCORES = 2, M_OUT = 3 };

template <int MODE, int SWZ>
static __device__ __forceinline__ void core256x128(
    const u16* __restrict__ Ab, int lda, const u16* __restrict__ Bb, int ldb,
    char* smem, int m0, int n0, int nk, void* __restrict__ Cbase, int ldc,
    const float* __restrict__ bias, const float* __restrict__ ksb,
    const float* __restrict__ vtab) {
  const int tid = threadIdx.x;
  const int lane = tid & 63;
  const int wid = tid >> 6;
  const int wm = wid >> 1, wn = wid & 1;  // 4 x 2 waves, wave owns 64x64

  char* As = smem;            // 256 rows x 128B = 32KB
  char* Bs = smem + 32768;    // 128 rows x 128B = 16KB

  // staging: per issue 512 thr x 16B = 8KB = 64 rows. Global source column
  // carries the inverse XOR swizzle (LDS dest stays linear for global_load_lds).
  const int r7 = (tid >> 3) & 7;
  const int cb = (tid & 7) << 4;
  const int gcol = SWZ ? (cb ^ (r7 << 4)) : cb;
  const int rbase_st = tid >> 3;  // row within 64-row issue group

  // ds_read constants: fragment row r = w*64 + m*16 + (lane&15); r&7 == lane&7
  const int aoff = (wm * 64 + (lane & 15)) * 128;
  const int boff = (wn * 64 + (lane & 15)) * 128;
  const int swz7 = SWZ ? (lane & 7) : 0;
  const int c0 = ((0 * 4 + (lane >> 4)) ^ swz7) << 4;  // ks=0 col bytes
  const int c1 = ((1 * 4 + (lane >> 4)) ^ swz7) << 4;  // ks=1 col bytes

  f32x4 acc[4][4];
#pragma unroll
  for (int m = 0; m < 4; ++m)
#pragma unroll
    for (int n = 0; n < 4; ++n) acc[m][n] = (f32x4){0.f, 0.f, 0.f, 0.f};

  for (int kt = 0; kt < nk; ++kt) {
    const int k0 = kt * 64;
#pragma unroll
    for (int i = 0; i < 4; ++i) {  // A: rows [64i, 64i+64)
      const char* ga = (const char*)(Ab + (size_t)(m0 + i * 64 + rbase_st) * lda + k0) + gcol;
      __builtin_amdgcn_global_load_lds(
          (const __attribute__((address_space(1))) void*)ga,
          (__attribute__((address_space(3))) void*)(As + i * 8192 + wid * 1024), 16, 0, 0);
    }
#pragma unroll
    for (int j = 0; j < 2; ++j) {  // B: rows [64j, 64j+64)
      const char* gb = (const char*)(Bb + (size_t)(n0 + j * 64 + rbase_st) * ldb + k0) + gcol;
      __builtin_amdgcn_global_load_lds(
          (const __attribute__((address_space(1))) void*)gb,
          (__attribute__((address_space(3))) void*)(Bs + j * 8192 + wid * 1024), 16, 0, 0);
    }
    __syncthreads();
#pragma unroll
    for (int ks = 0; ks < 2; ++ks) {
      const int cks = ks ? c1 : c0;
      bf16x8 af[4], bfv[4];
#pragma unroll
      for (int m = 0; m < 4; ++m) af[m] = *(const bf16x8*)(As + aoff + m * 2048 + cks);
#pragma unroll
      for (int n = 0; n < 4; ++n) bfv[n] = *(const bf16x8*)(Bs + boff + n * 2048 + cks);
#pragma unroll
      for (int m = 0; m < 4; ++m)
#pragma unroll
        for (int n = 0; n < 4; ++n)
          acc[m][n] = __builtin_amdgcn_mfma_f32_16x16x32_bf16(af[m], bfv[n], acc[m][n], 0, 0, 0);
    }
    __syncthreads();
  }

  // epilogue — C/D layout: col = lane&15, row = (lane>>4)*4 + reg  [m89]
  u16* C16 = (u16*)Cbase;
  float* Cf = (float*)Cbase;
#pragma unroll
  for (int m = 0; m < 4; ++m) {
#pragma unroll
    for (int n = 0; n < 4; ++n) {
      const int rb = m0 + wm * 64 + m * 16 + ((lane >> 4) << 2);
      const int c = n0 + wn * 64 + n * 16 + (lane & 15);
#pragma unroll
      for (int j = 0; j < 4; ++j) {
        const int r = rb + j;
        float v = acc[m][n][j];
        if (MODE == M_BIASN) {
          v += bias[c];
          C16[(size_t)r * ldc + c] = f2bf(v);
        } else if (MODE == M_BIASM) {
          v += bias[r];
          C16[(size_t)r * ldc + c] = f2bf(v);
        } else if (MODE == M_SCORES) {
          if (c <= r) v += ksb[r] * vtab[r - c];  // rel = t-s >= 0
          else v = 0.f;                           // causal mask
          C16[(size_t)r * ldc + c] = f2bf(v);
        } else {  // M_OUT
          Cf[(size_t)r * ldc + c] = v;
        }
      }
    }
  }
}

// ---- standard rectangular wrapper with bijective XCD swizzle ----
template <int MODE, int SWZ>
static __device__ __forceinline__ void rect_gemm(
    const u16* A, int lda, long long sA, const u16* B, int ldb, long long sB,
    void* Cv, int ldc, long long sC, int k_len, const float* bias) {
  const int nl = gridDim.x * gridDim.y;
  const int l = blockIdx.x + gridDim.x * blockIdx.y;
  const int q8 = nl >> 3;
  const int logical = (l & 7) * q8 + (l >> 3);
  const int gx = logical % gridDim.x;   // N-tile (128)
  const int gy = logical / gridDim.x;   // M-tile (256)
  const int z = blockIdx.z;
  __shared__ char smem[49152];
  core256x128<MODE, SWZ>(A + (size_t)z * sA, lda, B + (size_t)z * sB, ldb, smem,
                         gy * 256, gx * 128, k_len >> 6,
                         (char*)Cv + 0, ldc, bias, nullptr, nullptr);
  // note: Cbase z-offset folded below via wrapper kernels passing shifted Cv
}

__global__ __launch_bounds__(512, 4) void k_q_proj(  // E1: LINEAR LDS (m97-exact)
    const u16* A, const u16* B, u16* C, const float* bias) {
  const int nl = gridDim.x * gridDim.y;
  const int l = blockIdx.x + gridDim.x * blockIdx.y;
  const int logical = (l & 7) * (nl >> 3) + (l >> 3);
  const int gx = logical % gridDim.x, gy = logical / gridDim.x;
  __shared__ char smem[49152];
  core256x128<M_BIASN, 0>(A, 1024, B, 1024, smem, gy * 256, gx * 128, 16,
                          C, 1024, bias, nullptr, nullptr);
}
__global__ __launch_bounds__(512, 4) void k_k_proj(  // E2: XOR-swizzled LDS
    const u16* A, const u16* B, u16* C, const float* bias) {
  const int nl = gridDim.x * gridDim.y;
  const int l = blockIdx.x + gridDim.x * blockIdx.y;
  const int logical = (l & 7) * (nl >> 3) + (l >> 3);
  const int gx = logical % gridDim.x, gy = logical / gridDim.x;
  __shared__ char smem[49152];
  core256x128<M_BIASN, 1>(A, 1024, B, 1024, smem, gy * 256, gx * 128, 16,
                          C, 1024, bias, nullptr, nullptr);
}
__global__ __launch_bounds__(512, 4) void k_v_proj(  // V^T = Wv @ e^T (+bv per row)
    const u16* A, const u16* B, u16* C, const float* bias) {
  const int nl = gridDim.x * gridDim.y;
  const int l = blockIdx.x + gridDim.x * blockIdx.y;
  const int logical = (l & 7) * (nl >> 3) + (l >> 3);
  const int gx = logical % gridDim.x, gy = logical / gridDim.x;  // gx in [0,128), gy in [0,4)
  __shared__ char smem[49152];
  core256x128<M_BIASM, 1>(A, 1024, B, 1024, smem, gy * 256, gx * 128, 16,
                          C, 16384, bias, nullptr, nullptr);
}
__global__ __launch_bounds__(512, 4) void k_scores(  // triangular grid: 72 workers/z
    const u16* Q, const u16* K, u16* S, const float* ksum, const float* vtab) {
  // XCD-chunked bijection: 72 = 8 x 9
  const int h = (blockIdx.x & 7) * 9 + (blockIdx.x >> 3);
  int gy = 0;
#pragma unroll
  for (int q = 1; q < 8; ++q) if (q * q + q <= h) gy = q;   // cum(gy) = gy^2+gy
  const int gx = h - (gy * gy + gy);                         // gx <= 2*gy+1
  const int z = blockIdx.z;
  __shared__ char smem[49152];
  core256x128<M_SCORES, 1>(Q + (size_t)z * 2048 * 1024, 1024,
                           K + (size_t)z * 2048 * 1024, 1024, smem,
                           gy * 256, gx * 128, 16,
                           S + (size_t)z * 2048 * 2048, 2048,
                           nullptr, ksum + (size_t)z * 2048, vtab);
}
__global__ __launch_bounds__(512, 4) void k_out(  // paired (gy, 7-gy): uniform 36 K-tiles
    const u16* S, const u16* VT, float* O) {
  const int nl = gridDim.x * gridDim.y;
  const int l = blockIdx.x + gridDim.x * blockIdx.y;
  const int logical = (l & 7) * (nl >> 3) + (l >> 3);
  const int gx = logical % gridDim.x;   // d-chunk in [0,8)
  const int p = logical / gridDim.x;    // pair id in [0,4)
  const int z = blockIdx.z;
  __shared__ char smem[49152];
#pragma unroll
  for (int sub = 0; sub < 2; ++sub) {
    const int gy = sub ? 7 - p : p;
    const int nk = (gy + 1) * 4;  // causal K-extent (gy+1)*256 cols of scores
    core256x128<M_OUT, 1>(S + (size_t)z * 2048 * 2048, 2048,
                          VT + (size_t)z * 2048, 16384, smem,
                          gy * 256, gx * 128, nk,
                          O + (size_t)z * 2048 * 1024, 1024,
                          nullptr, nullptr, nullptr);
    if (sub == 0) __syncthreads();
  }
}

extern "C" void kernel_launch(void* const* d_in, const int* in_sizes, int n_in,
                              void* d_out, int out_size, void* d_ws, size_t ws_size,
                              hipStream_t stream) {
  (void)in_sizes; (void)n_in; (void)out_size; (void)ws_size;
  const float* e    = (const float*)d_in[0];
  const float* res  = (const float*)d_in[1];
  const float* Wq_w = (const float*)d_in[2];
  const float* Wq_b = (const float*)d_in[3];
  const float* Wk_w = (const float*)d_in[4];
  const float* Wk_b = (const float*)d_in[5];
  const float* Wv_w = (const float*)d_in[6];
  const float* Wv_b = (const float*)d_in[7];
  const float* vtab = (const float*)d_in[8];

  char* ws = (char*)d_ws;
  const size_t SZ = 33554432;  // 32 MiB = one bf16 (16384x1024) buffer
  u16* ebf = (u16*)(ws);
  u16* rbf = (u16*)(ws + SZ);
  u16* Qb  = (u16*)(ws + 2 * SZ);
  u16* Kb  = (u16*)(ws + 3 * SZ);
  u16* VT  = (u16*)(ws + 4 * SZ);
  u16* Wqb = (u16*)(ws + 5 * SZ);
  u16* Wkb = (u16*)(ws + 5 * SZ + 2097152);
  u16* Wvb = (u16*)(ws + 5 * SZ + 2 * 2097152);
  float* ksum = (float*)(ws + 5 * SZ + 3 * 2097152);
  u16* scores = (u16*)(ws);  // reuse ebf+rbf (64 MB); written after last read of ebf

  conv_big<<<dim3(8192, 1, 2), 256, 0, stream>>>(e, res, ebf, rbf);
  conv_w<<<dim3(512, 1, 3), 256, 0, stream>>>(Wq_w, Wk_w, Wv_w, Wqb, Wkb, Wvb);

  // Q = e @ Wq^T + bq : M=16384 (64 tiles), N=1024 (8 tiles) -> 512 blocks
  k_q_proj<<<dim3(8, 64, 1), 512, 0, stream>>>(ebf, Wqb, Qb, Wq_b);
  // K = res @ Wk^T + bk
  k_k_proj<<<dim3(8, 64, 1), 512, 0, stream>>>(rbf, Wkb, Kb, Wk_b);
  // V^T = Wv @ e^T + bv : M=1024 (4 tiles), N=16384 (128 tiles) -> 512 blocks
  k_v_proj<<<dim3(128, 4, 1), 512, 0, stream>>>(Wvb, ebf, VT, Wv_b);

  ksum_kernel<<<4096, 256, 0, stream>>>(Kb, ksum);

  // scores: triangular 72 workers/z x 8 z = 576 blocks
  k_scores<<<dim3(72, 1, 8), 512, 0, stream>>>(Qb, Kb, scores, ksum, vtab);

  // out: 8 d-chunks x 4 pairs x 8 z = 256 blocks, uniform 36 K-tiles each
  k_out<<<dim3(8, 4, 8), 512, 0, stream>>>(scores, VT, (float*)d_out);
}

// Round 6
// 292.415 us; speedup vs baseline: 1.1854x; 1.0411x over previous
//
#include <hip/hip_runtime.h>

typedef unsigned short u16;
typedef __attribute__((ext_vector_type(8))) short bf16x8;
typedef __attribute__((ext_vector_type(8))) unsigned short u16x8;
typedef __attribute__((ext_vector_type(4))) float f32x4;

static __device__ __forceinline__ u16 f2bf(float f) {
  unsigned u = __float_as_uint(f);
  u += 0x7FFFu + ((u >> 16) & 1u);   // RNE
  return (u16)(u >> 16);
}
static __device__ __forceinline__ float bf2f(u16 h) {
  return __uint_as_float(((unsigned)h) << 16);
}

// ---------- fp32 -> bf16 converts (fused via grid.z) ----------
__global__ __launch_bounds__(256) void conv_big(const float* __restrict__ e,
                                                const float* __restrict__ res,
                                                u16* __restrict__ eb, u16* __restrict__ rb) {
  int i = blockIdx.x * 256 + threadIdx.x;
  const float* in = blockIdx.z ? res : e;
  u16* out = blockIdx.z ? rb : eb;
  const float4* p = (const float4*)in + (size_t)i * 2;
  float4 a = p[0], b = p[1];
  u16x8 r;
  r[0] = f2bf(a.x); r[1] = f2bf(a.y); r[2] = f2bf(a.z); r[3] = f2bf(a.w);
  r[4] = f2bf(b.x); r[5] = f2bf(b.y); r[6] = f2bf(b.z); r[7] = f2bf(b.w);
  ((u16x8*)out)[i] = r;
}
__global__ __launch_bounds__(256) void conv_w(const float* __restrict__ w0,
                                              const float* __restrict__ w1,
                                              const float* __restrict__ w2,
                                              u16* __restrict__ o0, u16* __restrict__ o1,
                                              u16* __restrict__ o2) {
  int i = blockIdx.x * 256 + threadIdx.x;
  const float* in = blockIdx.z == 0 ? w0 : (blockIdx.z == 1 ? w1 : w2);
  u16* out = blockIdx.z == 0 ? o0 : (blockIdx.z == 1 ? o1 : o2);
  const float4* p = (const float4*)in + (size_t)i * 2;
  float4 a = p[0], b = p[1];
  u16x8 r;
  r[0] = f2bf(a.x); r[1] = f2bf(a.y); r[2] = f2bf(a.z); r[3] = f2bf(a.w);
  r[4] = f2bf(b.x); r[5] = f2bf(b.y); r[6] = f2bf(b.z); r[7] = f2bf(b.w);
  ((u16x8*)out)[i] = r;
}

// ---------- row-sum of K (bf16, 1024 cols) -> fp32 ----------
__global__ __launch_bounds__(256) void ksum_kernel(const u16* __restrict__ K,
                                                   float* __restrict__ out) {
  int row = blockIdx.x * 4 + (threadIdx.x >> 6);
  int lane = threadIdx.x & 63;
  const u16x8* p = (const u16x8*)(K + (size_t)row * 1024);
  float s = 0.f;
#pragma unroll
  for (int it = 0; it < 2; ++it) {
    u16x8 v = p[lane + it * 64];
#pragma unroll
    for (int j = 0; j < 8; ++j) s += bf2f(v[j]);
  }
#pragma unroll
  for (int off = 32; off >= 1; off >>= 1) s += __shfl_down(s, off);
  if (lane == 0) out[row] = s;
}

// =============== 128x128 bf16 GEMM core (m97-exact + T2 swizzle) ===============
// C = A(MxK) * B(NxK)^T. 256 thr / 4 waves (2x2, wave tile 64x64, acc 4x4),
// single 32KB LDS buffer, BK=64, 2 __syncthreads per K-step,
// global_load_lds width 16 with inverse-XOR-swizzled global source.
// launch_bounds(256,3) -> 3 blocks/CU co-residency (m114 wave-overlap regime).
enum { M_BIASN = 0, M_BIASM = 1, M_SCORES = 2, M_OUT = 3 };

template <int MODE>
static __device__ __forceinline__ void core128(
    const u16* __restrict__ Ab, int lda, const u16* __restrict__ Bb, int ldb,
    char* smem, int m0, int n0, int nk, void* __restrict__ Cbase, int ldc,
    const float* __restrict__ bias, const float* __restrict__ ksb,
    const float* __restrict__ vtab) {
  const int tid = threadIdx.x;
  const int lane = tid & 63;
  const int wid = tid >> 6;
  const int wm = wid >> 1, wn = wid & 1;

  char* As = smem;           // 128 rows x 128B = 16KB
  char* Bs = smem + 16384;   // 16KB

  // staging: per issue 256 thr x 16B = 4KB = 32 rows; global col pre-swizzled
  const int rbase_st = tid >> 3;                 // 0..31
  const int gcol = ((tid & 7) << 4) ^ ((rbase_st & 7) << 4);

  // ds_read constants: fragment row r = w*64 + m*16 + (lane&15); r&7 == lane&7
  const int aoff = (wm * 64 + (lane & 15)) * 128;
  const int boff = (wn * 64 + (lane & 15)) * 128;
  const int c0 = ((0 * 4 + (lane >> 4)) ^ (lane & 7)) << 4;
  const int c1 = ((1 * 4 + (lane >> 4)) ^ (lane & 7)) << 4;

  f32x4 acc[4][4];
#pragma unroll
  for (int m = 0; m < 4; ++m)
#pragma unroll
    for (int n = 0; n < 4; ++n) acc[m][n] = (f32x4){0.f, 0.f, 0.f, 0.f};

  for (int kt = 0; kt < nk; ++kt) {
    const int k0 = kt * 64;
#pragma unroll
    for (int i = 0; i < 4; ++i) {  // A rows [32i, 32i+32)
      const char* ga = (const char*)(Ab + (size_t)(m0 + i * 32 + rbase_st) * lda + k0) + gcol;
      __builtin_amdgcn_global_load_lds(
          (const __attribute__((address_space(1))) void*)ga,
          (__attribute__((address_space(3))) void*)(As + i * 4096 + wid * 1024), 16, 0, 0);
    }
#pragma unroll
    for (int i = 0; i < 4; ++i) {  // B rows [32i, 32i+32)
      const char* gb = (const char*)(Bb + (size_t)(n0 + i * 32 + rbase_st) * ldb + k0) + gcol;
      __builtin_amdgcn_global_load_lds(
          (const __attribute__((address_space(1))) void*)gb,
          (__attribute__((address_space(3))) void*)(Bs + i * 4096 + wid * 1024), 16, 0, 0);
    }
    __syncthreads();
#pragma unroll
    for (int ks = 0; ks < 2; ++ks) {
      const int cks = ks ? c1 : c0;
      bf16x8 af[4], bfv[4];
#pragma unroll
      for (int m = 0; m < 4; ++m) af[m] = *(const bf16x8*)(As + aoff + m * 2048 + cks);
#pragma unroll
      for (int n = 0; n < 4; ++n) bfv[n] = *(const bf16x8*)(Bs + boff + n * 2048 + cks);
#pragma unroll
      for (int m = 0; m < 4; ++m)
#pragma unroll
        for (int n = 0; n < 4; ++n)
          acc[m][n] = __builtin_amdgcn_mfma_f32_16x16x32_bf16(af[m], bfv[n], acc[m][n], 0, 0, 0);
    }
    __syncthreads();
  }

  // epilogue — C/D layout: col = lane&15, row = (lane>>4)*4 + reg  [m89]
  u16* C16 = (u16*)Cbase;
  float* Cf = (float*)Cbase;
#pragma unroll
  for (int m = 0; m < 4; ++m) {
#pragma unroll
    for (int n = 0; n < 4; ++n) {
      const int rb = m0 + wm * 64 + m * 16 + ((lane >> 4) << 2);
      const int c = n0 + wn * 64 + n * 16 + (lane & 15);
#pragma unroll
      for (int j = 0; j < 4; ++j) {
        const int r = rb + j;
        float v = acc[m][n][j];
        if (MODE == M_BIASN) {
          v += bias[c];
          C16[(size_t)r * ldc + c] = f2bf(v);
        } else if (MODE == M_BIASM) {
          v += bias[r];
          C16[(size_t)r * ldc + c] = f2bf(v);
        } else if (MODE == M_SCORES) {
          if (c <= r) v += ksb[r] * vtab[r - c];  // rel = t-s >= 0
          else v = 0.f;                           // causal mask
          C16[(size_t)r * ldc + c] = f2bf(v);
        } else {  // M_OUT
          Cf[(size_t)r * ldc + c] = v;
        }
      }
    }
  }
}

static __device__ __forceinline__ int2 xcd_swz_xy() {
  const int nl = gridDim.x * gridDim.y;
  const int l = blockIdx.x + gridDim.x * blockIdx.y;
  const int logical = (l & 7) * (nl >> 3) + (l >> 3);  // nl % 8 == 0 everywhere
  return make_int2(logical % gridDim.x, logical / gridDim.x);
}

// Q and K projections in one launch (z selects operand set)
__global__ __launch_bounds__(256, 3) void k_qk_proj(
    const u16* eb, const u16* rb, const u16* Wq, const u16* Wk,
    const float* bq, const float* bk, u16* Q, u16* K) {
  int2 g = xcd_swz_xy();
  const int zz = blockIdx.z;
  const u16* A = zz ? rb : eb;
  const u16* B = zz ? Wk : Wq;
  const float* bias = zz ? bk : bq;
  u16* C = zz ? K : Q;
  __shared__ char smem[32768];
  core128<M_BIASN>(A, 1024, B, 1024, smem, g.y * 128, g.x * 128, 16,
                   C, 1024, bias, nullptr, nullptr);
}
// V^T = Wv @ e^T + bv (bias per row d)
__global__ __launch_bounds__(256, 3) void k_v_proj(
    const u16* Wv, const u16* eb, u16* VT, const float* bv) {
  int2 g = xcd_swz_xy();  // gx in [0,128) over N=16384, gy in [0,8) over M=1024
  __shared__ char smem[32768];
  core128<M_BIASM>(Wv, 1024, eb, 1024, smem, g.y * 128, g.x * 128, 16,
                   VT, 16384, bv, nullptr, nullptr);
}
// scores: exact triangular grid, 136 tiles/z (136 = 8 x 17, XCD-chunked)
__global__ __launch_bounds__(256, 3) void k_scores(
    const u16* Q, const u16* K, u16* S, const float* ksum, const float* vtab) {
  const int h = (blockIdx.x & 7) * 17 + (blockIdx.x >> 3);
  int gy = 0;
#pragma unroll
  for (int q = 1; q < 16; ++q) if (q * (q + 1) / 2 <= h) gy = q;
  const int gx = h - gy * (gy + 1) / 2;  // gx <= gy
  const int z = blockIdx.z;
  __shared__ char smem[32768];
  core128<M_SCORES>(Q + (size_t)z * 2048 * 1024, 1024,
                    K + (size_t)z * 2048 * 1024, 1024, smem,
                    gy * 128, gx * 128, 16,
                    S + (size_t)z * 2048 * 2048, 2048,
                    nullptr, ksum + (size_t)z * 2048, vtab);
}
// out: pairs (gy, 15-gy) -> uniform 34 K-steps; 8 gx x 8 pairs x 8 z = 512 blocks
__global__ __launch_bounds__(256, 3) void k_out(
    const u16* S, const u16* VT, float* O) {
  int2 g = xcd_swz_xy();
  const int gx = g.x;      // d-tile in [0,8)
  const int p = g.y;       // pair id in [0,8)
  const int z = blockIdx.z;
  __shared__ char smem[32768];
#pragma unroll
  for (int sub = 0; sub < 2; ++sub) {
    const int gy = sub ? 15 - p : p;
    const int nk = (gy + 1) * 2;  // causal extent (gy+1)*128 score-cols
    core128<M_OUT>(S + (size_t)z * 2048 * 2048, 2048,
                   VT + (size_t)z * 2048, 16384, smem,
                   gy * 128, gx * 128, nk,
                   O + (size_t)z * 2048 * 1024, 1024,
                   nullptr, nullptr, nullptr);
    if (sub == 0) __syncthreads();
  }
}

extern "C" void kernel_launch(void* const* d_in, const int* in_sizes, int n_in,
                              void* d_out, int out_size, void* d_ws, size_t ws_size,
                              hipStream_t stream) {
  (void)in_sizes; (void)n_in; (void)out_size; (void)ws_size;
  const float* e    = (const float*)d_in[0];
  const float* res  = (const float*)d_in[1];
  const float* Wq_w = (const float*)d_in[2];
  const float* Wq_b = (const float*)d_in[3];
  const float* Wk_w = (const float*)d_in[4];
  const float* Wk_b = (const float*)d_in[5];
  const float* Wv_w = (const float*)d_in[6];
  const float* Wv_b = (const float*)d_in[7];
  const float* vtab = (const float*)d_in[8];

  char* ws = (char*)d_ws;
  const size_t SZ = 33554432;  // 32 MiB = one bf16 (16384x1024) buffer
  u16* ebf = (u16*)(ws);
  u16* rbf = (u16*)(ws + SZ);
  u16* Qb  = (u16*)(ws + 2 * SZ);
  u16* Kb  = (u16*)(ws + 3 * SZ);
  u16* VT  = (u16*)(ws + 4 * SZ);
  u16* Wqb = (u16*)(ws + 5 * SZ);
  u16* Wkb = (u16*)(ws + 5 * SZ + 2097152);
  u16* Wvb = (u16*)(ws + 5 * SZ + 2 * 2097152);
  float* ksum = (float*)(ws + 5 * SZ + 3 * 2097152);
  u16* scores = (u16*)(ws);  // reuse ebf+rbf (64 MB); written after last read of ebf

  conv_big<<<dim3(8192, 1, 2), 256, 0, stream>>>(e, res, ebf, rbf);
  conv_w<<<dim3(512, 1, 3), 256, 0, stream>>>(Wq_w, Wk_w, Wv_w, Wqb, Wkb, Wvb);

  // Q/K projections: M=16384 (128 tiles), N=1024 (8 tiles) -> 1024 blocks x 2
  k_qk_proj<<<dim3(8, 128, 2), 256, 0, stream>>>(ebf, rbf, Wqb, Wkb, Wq_b, Wk_b, Qb, Kb);
  // V^T: M=1024 (8 tiles), N=16384 (128 tiles) -> 1024 blocks
  k_v_proj<<<dim3(128, 8, 1), 256, 0, stream>>>(Wvb, ebf, VT, Wv_b);

  ksum_kernel<<<4096, 256, 0, stream>>>(Kb, ksum);

  // scores: 136 triangular tiles/z x 8 z = 1088 blocks
  k_scores<<<dim3(136, 1, 8), 256, 0, stream>>>(Qb, Kb, scores, ksum, vtab);

  // out: 8 d-tiles x 8 pairs x 8 z = 512 blocks, uniform 34 K-steps each
  k_out<<<dim3(8, 8, 8), 256, 0, stream>>>(scores, VT, (float*)d_out);
}

// Round 7
// 256.642 us; speedup vs baseline: 1.3506x; 1.1394x over previous
//
#include <hip/hip_runtime.h>

typedef unsigned short u16;
typedef __attribute__((ext_vector_type(8))) short bf16x8;
typedef __attribute__((ext_vector_type(8))) unsigned short u16x8;
typedef __attribute__((ext_vector_type(4))) float f32x4;

static __device__ __forceinline__ u16 f2bf(float f) {
  unsigned u = __float_as_uint(f);
  u += 0x7FFFu + ((u >> 16) & 1u);   // RNE
  return (u16)(u >> 16);
}
static __device__ __forceinline__ float bf2f(u16 h) {
  return __uint_as_float(((unsigned)h) << 16);
}

// ---------- fp32 -> bf16 converts ----------
__global__ __launch_bounds__(256) void conv_big(const float* __restrict__ e,
                                                const float* __restrict__ res,
                                                u16* __restrict__ eb, u16* __restrict__ rb) {
  int i = blockIdx.x * 256 + threadIdx.x;
  const float* in = blockIdx.z ? res : e;
  u16* out = blockIdx.z ? rb : eb;
  const float4* p = (const float4*)in + (size_t)i * 2;
  float4 a = p[0], b = p[1];
  u16x8 r;
  r[0] = f2bf(a.x); r[1] = f2bf(a.y); r[2] = f2bf(a.z); r[3] = f2bf(a.w);
  r[4] = f2bf(b.x); r[5] = f2bf(b.y); r[6] = f2bf(b.z); r[7] = f2bf(b.w);
  ((u16x8*)out)[i] = r;
}
__global__ __launch_bounds__(256) void conv_w(const float* __restrict__ w0,
                                              const float* __restrict__ w1,
                                              const float* __restrict__ w2,
                                              u16* __restrict__ o0, u16* __restrict__ o1,
                                              u16* __restrict__ o2) {
  int i = blockIdx.x * 256 + threadIdx.x;
  const float* in = blockIdx.z == 0 ? w0 : (blockIdx.z == 1 ? w1 : w2);
  u16* out = blockIdx.z == 0 ? o0 : (blockIdx.z == 1 ? o1 : o2);
  const float4* p = (const float4*)in + (size_t)i * 2;
  float4 a = p[0], b = p[1];
  u16x8 r;
  r[0] = f2bf(a.x); r[1] = f2bf(a.y); r[2] = f2bf(a.z); r[3] = f2bf(a.w);
  r[4] = f2bf(b.x); r[5] = f2bf(b.y); r[6] = f2bf(b.z); r[7] = f2bf(b.w);
  ((u16x8*)out)[i] = r;
}

// ---------- row-sum of K (bf16, 1024 cols) -> fp32 ----------
__global__ __launch_bounds__(256) void ksum_kernel(const u16* __restrict__ K,
                                                   float* __restrict__ out) {
  int row = blockIdx.x * 4 + (threadIdx.x >> 6);
  int lane = threadIdx.x & 63;
  const u16x8* p = (const u16x8*)(K + (size_t)row * 1024);
  float s = 0.f;
#pragma unroll
  for (int it = 0; it < 2; ++it) {
    u16x8 v = p[lane + it * 64];
#pragma unroll
    for (int j = 0; j < 8; ++j) s += bf2f(v[j]);
  }
#pragma unroll
  for (int off = 32; off >= 1; off >>= 1) s += __shfl_down(s, off);
  if (lane == 0) out[row] = s;
}

// =============== 128x128 bf16 GEMM core (m97 + T2 swizzle) ===============
enum { M_BIASN = 0, M_BIASM = 1, M_SCORES = 2, M_OUT = 3 };

template <int MODE>
static __device__ __forceinline__ void core128(
    const u16* __restrict__ Ab, int lda, const u16* __restrict__ Bb, int ldb,
    char* smem, int m0, int n0, int nk, void* __restrict__ Cbase, int ldc,
    const float* __restrict__ bias, const float* __restrict__ ksb,
    const float* __restrict__ vtab) {
  const int tid = threadIdx.x;
  const int lane = tid & 63;
  const int wid = tid >> 6;
  const int wm = wid >> 1, wn = wid & 1;

  char* As = smem;           // 128 rows x 128B = 16KB
  char* Bs = smem + 16384;   // 16KB

  const int rbase_st = tid >> 3;                 // 0..31
  const int gcol = ((tid & 7) << 4) ^ ((rbase_st & 7) << 4);

  const int aoff = (wm * 64 + (lane & 15)) * 128;
  const int boff = (wn * 64 + (lane & 15)) * 128;
  const int c0 = ((0 * 4 + (lane >> 4)) ^ (lane & 7)) << 4;
  const int c1 = ((1 * 4 + (lane >> 4)) ^ (lane & 7)) << 4;

  f32x4 acc[4][4];
#pragma unroll
  for (int m = 0; m < 4; ++m)
#pragma unroll
    for (int n = 0; n < 4; ++n) acc[m][n] = (f32x4){0.f, 0.f, 0.f, 0.f};

  for (int kt = 0; kt < nk; ++kt) {
    const int k0 = kt * 64;
#pragma unroll
    for (int i = 0; i < 4; ++i) {
      const char* ga = (const char*)(Ab + (size_t)(m0 + i * 32 + rbase_st) * lda + k0) + gcol;
      __builtin_amdgcn_global_load_lds(
          (const __attribute__((address_space(1))) void*)ga,
          (__attribute__((address_space(3))) void*)(As + i * 4096 + wid * 1024), 16, 0, 0);
    }
#pragma unroll
    for (int i = 0; i < 4; ++i) {
      const char* gb = (const char*)(Bb + (size_t)(n0 + i * 32 + rbase_st) * ldb + k0) + gcol;
      __builtin_amdgcn_global_load_lds(
          (const __attribute__((address_space(1))) void*)gb,
          (__attribute__((address_space(3))) void*)(Bs + i * 4096 + wid * 1024), 16, 0, 0);
    }
    __syncthreads();
#pragma unroll
    for (int ks = 0; ks < 2; ++ks) {
      const int cks = ks ? c1 : c0;
      bf16x8 af[4], bfv[4];
#pragma unroll
      for (int m = 0; m < 4; ++m) af[m] = *(const bf16x8*)(As + aoff + m * 2048 + cks);
#pragma unroll
      for (int n = 0; n < 4; ++n) bfv[n] = *(const bf16x8*)(Bs + boff + n * 2048 + cks);
#pragma unroll
      for (int m = 0; m < 4; ++m)
#pragma unroll
        for (int n = 0; n < 4; ++n)
          acc[m][n] = __builtin_amdgcn_mfma_f32_16x16x32_bf16(af[m], bfv[n], acc[m][n], 0, 0, 0);
    }
    __syncthreads();
  }

  // epilogue — C/D layout: col = lane&15, row = (lane>>4)*4 + reg  [m89]
  u16* C16 = (u16*)Cbase;
  float* Cf = (float*)Cbase;
#pragma unroll
  for (int m = 0; m < 4; ++m) {
#pragma unroll
    for (int n = 0; n < 4; ++n) {
      const int rb = m0 + wm * 64 + m * 16 + ((lane >> 4) << 2);
      const int c = n0 + wn * 64 + n * 16 + (lane & 15);
#pragma unroll
      for (int j = 0; j < 4; ++j) {
        const int r = rb + j;
        float v = acc[m][n][j];
        if (MODE == M_BIASN) {
          v += bias[c];
          C16[(size_t)r * ldc + c] = f2bf(v);
        } else if (MODE == M_BIASM) {
          v += bias[r];
          C16[(size_t)r * ldc + c] = f2bf(v);
        } else if (MODE == M_SCORES) {
          if (c <= r) v += ksb[r] * vtab[r - c];  // rel = t-s >= 0
          else v = 0.f;                           // causal mask
          C16[(size_t)r * ldc + c] = f2bf(v);
        } else {  // M_OUT
          Cf[(size_t)r * ldc + c] = v;
        }
      }
    }
  }
}

// ---- Q+K projections: flat 2048 blocks. xcd = l&7 owns m-rows
// [xcd*2048, +2048) for BOTH operands; Q-phase (idx<128) then K-phase.
__global__ __launch_bounds__(256, 4) void k_qk_proj(
    const u16* eb, const u16* rb, const u16* Wq, const u16* Wk,
    const float* bq, const float* bk, u16* Q, u16* K) {
  const int l = blockIdx.x;
  const int xcd = l & 7;
  const int idx = l >> 3;            // 0..255
  const bool isK = idx >= 128;
  const int j = idx & 127;
  const int gy = xcd * 16 + (j >> 3);  // m-tile in [0,128)
  const int gx = j & 7;                // n-tile in [0,8)
  const u16* A = isK ? rb : eb;
  const u16* B = isK ? Wk : Wq;
  const float* bias = isK ? bk : bq;
  u16* C = isK ? K : Q;
  __shared__ char smem[32768];
  core128<M_BIASN>(A, 1024, B, 1024, smem, gy * 128, gx * 128, 16,
                   C, 1024, bias, nullptr, nullptr);
}
// ---- V^T = Wv @ e^T + bv: flat 1024 blocks. xcd owns e-rows (t) strip.
__global__ __launch_bounds__(256, 4) void k_v_proj(
    const u16* Wv, const u16* eb, u16* VT, const float* bv) {
  const int l = blockIdx.x;
  const int xcd = l & 7;
  const int idx = l >> 3;              // 0..127
  const int gxt = xcd * 16 + (idx >> 3);  // t-tile in [0,128)
  const int gyd = idx & 7;                // d-tile in [0,8)
  __shared__ char smem[32768];
  core128<M_BIASM>(Wv, 1024, eb, 1024, smem, gyd * 128, gxt * 128, 16,
                   VT, 16384, bv, nullptr, nullptr);
}
// ---- scores: flat 1088 blocks. xcd = l&7 = z (whole batch per XCD; working
// set Q_z + K_z = 8MB). h = l>>3 in [0,136) decodes the lower triangle.
__global__ __launch_bounds__(256, 4) void k_scores(
    const u16* Q, const u16* K, u16* S, const float* ksum, const float* vtab) {
  const int l = blockIdx.x;
  const int z = l & 7;
  const int h = l >> 3;
  int gy = 0;
#pragma unroll
  for (int q = 1; q < 16; ++q) if (q * (q + 1) / 2 <= h) gy = q;
  const int gx = h - gy * (gy + 1) / 2;  // gx <= gy
  __shared__ char smem[32768];
  core128<M_SCORES>(Q + (size_t)z * 2048 * 1024, 1024,
                    K + (size_t)z * 2048 * 1024, 1024, smem,
                    gy * 128, gx * 128, 16,
                    S + (size_t)z * 2048 * 2048, 2048,
                    nullptr, ksum + (size_t)z * 2048, vtab);
}
// ---- out: flat 1024 blocks. xcd = z; gy descending (longest-first), gx
// innermost so the 8 blocks sharing an S-strip are dispatch-adjacent.
__global__ __launch_bounds__(256, 4) void k_out(
    const u16* S, const u16* VT, float* O) {
  const int l = blockIdx.x;
  const int z = l & 7;
  const int idx = l >> 3;              // 0..127
  const int gy = 15 - (idx >> 3);      // q-tile, 15..0
  const int gx = idx & 7;              // d-tile
  const int nk = (gy + 1) * 2;         // causal extent (gy+1)*128 score-cols
  __shared__ char smem[32768];
  core128<M_OUT>(S + (size_t)z * 2048 * 2048, 2048,
                 VT + (size_t)z * 2048, 16384, smem,
                 gy * 128, gx * 128, nk,
                 O + (size_t)z * 2048 * 1024, 1024,
                 nullptr, nullptr, nullptr);
}

extern "C" void kernel_launch(void* const* d_in, const int* in_sizes, int n_in,
                              void* d_out, int out_size, void* d_ws, size_t ws_size,
                              hipStream_t stream) {
  (void)in_sizes; (void)n_in; (void)out_size; (void)ws_size;
  const float* e    = (const float*)d_in[0];
  const float* res  = (const float*)d_in[1];
  const float* Wq_w = (const float*)d_in[2];
  const float* Wq_b = (const float*)d_in[3];
  const float* Wk_w = (const float*)d_in[4];
  const float* Wk_b = (const float*)d_in[5];
  const float* Wv_w = (const float*)d_in[6];
  const float* Wv_b = (const float*)d_in[7];
  const float* vtab = (const float*)d_in[8];

  char* ws = (char*)d_ws;
  const size_t SZ = 33554432;  // 32 MiB = one bf16 (16384x1024) buffer
  u16* ebf = (u16*)(ws);
  u16* rbf = (u16*)(ws + SZ);
  u16* Qb  = (u16*)(ws + 2 * SZ);
  u16* Kb  = (u16*)(ws + 3 * SZ);
  u16* VT  = (u16*)(ws + 4 * SZ);
  u16* Wqb = (u16*)(ws + 5 * SZ);
  u16* Wkb = (u16*)(ws + 5 * SZ + 2097152);
  u16* Wvb = (u16*)(ws + 5 * SZ + 2 * 2097152);
  float* ksum = (float*)(ws + 5 * SZ + 3 * 2097152);
  u16* scores = (u16*)(ws);  // reuse ebf+rbf (64 MB); written after last read of ebf

  conv_big<<<dim3(8192, 1, 2), 256, 0, stream>>>(e, res, ebf, rbf);
  conv_w<<<dim3(512, 1, 3), 256, 0, stream>>>(Wq_w, Wk_w, Wv_w, Wqb, Wkb, Wvb);

  // Q/K projections: 2048 flat blocks, per-XCD m-strips
  k_qk_proj<<<dim3(2048, 1, 1), 256, 0, stream>>>(ebf, rbf, Wqb, Wkb, Wq_b, Wk_b, Qb, Kb);
  // V^T: 1024 flat blocks, per-XCD t-strips
  k_v_proj<<<dim3(1024, 1, 1), 256, 0, stream>>>(Wvb, ebf, VT, Wv_b);

  ksum_kernel<<<4096, 256, 0, stream>>>(Kb, ksum);

  // scores: 1088 flat blocks, batch z pinned to XCD z
  k_scores<<<dim3(1088, 1, 1), 256, 0, stream>>>(Qb, Kb, scores, ksum, vtab);

  // out: 1024 flat blocks, batch z pinned to XCD z, longest tiles first
  k_out<<<dim3(1024, 1, 1), 256, 0, stream>>>(scores, VT, (float*)d_out);
}